// Round 3
// baseline (349.246 us; speedup 1.0000x reference)
//
#include <hip/hip_runtime.h>
#include <hip/hip_bf16.h>

#define BATCH 4096

typedef __attribute__((ext_vector_type(8))) short short8;
typedef __attribute__((ext_vector_type(4))) short short4_t;
typedef __attribute__((ext_vector_type(4))) float f32x4;

#define MFMA_BF16 __builtin_amdgcn_mfma_f32_16x16x32_bf16

__device__ __forceinline__ float frelu(float v) { return v > 0.f ? v : 0.f; }
__device__ __forceinline__ unsigned short f2bf(float f) {
    return __builtin_bit_cast(unsigned short, __float2bfloat16(f));
}

// ---------------- prep: permute+cvt weights to bf16 K-contiguous layouts; init out ----------------
// w1p[oc][k] straight cast (layout is identity); w2p[oc][khw*32+ic]; w3p[oc][khw*64+ic];
// w4p[n][pos*64+oc]; out[0..8191]=b5; ave tail zero.
__global__ __launch_bounds__(256) void prep_kernel(const float* __restrict__ w1, const float* __restrict__ w2,
                                                   const float* __restrict__ w3, const float* __restrict__ w4,
                                                   const float* __restrict__ b5,
                                                   unsigned short* __restrict__ w1p, unsigned short* __restrict__ w2p,
                                                   unsigned short* __restrict__ w3p, unsigned short* __restrict__ w4p,
                                                   float* __restrict__ out) {
    int idx = blockIdx.x * 256 + threadIdx.x;
    if (idx < 6144) {
        w1p[idx] = f2bf(w1[idx]);
    } else if (idx < 24576) {
        int j = idx - 6144;
        int oc = j / 288, k = j % 288;
        int khw = k / 32, ic = k % 32;
        w2p[j] = f2bf(w2[oc * 288 + ic * 9 + khw]);
    } else if (idx < 61440) {
        int j = idx - 24576;
        int oc = j / 576, k = j % 576;
        int khw = k / 64, ic = k % 64;
        w3p[j] = f2bf(w3[oc * 576 + ic * 9 + khw]);
    } else if (idx < 552960) {
        int j = idx - 61440;
        int n = j / 960, k = j % 960;
        int pos = k / 64, oc = k % 64;
        w4p[j] = f2bf(w4[n * 960 + oc * 15 + pos]);
    } else if (idx < 561152) {
        int j = idx - 552960;
        out[j] = b5[j & 1];
    } else if (idx < 561367) {
        out[8192 + (idx - 561152)] = 0.f;
    }
}

// ---------------- fused conv1+conv2+conv3: one block per image, all intermediates in LDS ----------------
// LDS budget 20.4 KB -> 8 blocks/CU. x2l overlays the dead image buffer (conv1 accs held in regs
// across a barrier). redbuf img-major for coalesced export.
__global__ __launch_bounds__(256, 8) void fused_convs(const float* __restrict__ x,
                                                      const unsigned short* __restrict__ w1p, const float* __restrict__ b1,
                                                      const unsigned short* __restrict__ w2p, const float* __restrict__ b2,
                                                      const unsigned short* __restrict__ w3p, const float* __restrict__ b3,
                                                      unsigned short* __restrict__ x6, float* __restrict__ redbuf) {
    constexpr int RS = 68;                                   // image row stride (shorts)
    __shared__ __align__(16) unsigned short ub[3 * 48 * RS]; // 9792 shorts = 19584 B, multi-use
    __shared__ float red[215];                               // 0..164 ave1 | 165..199 ave2 | 200..214 ave3
    unsigned short* x2l = ub;          // [165][36] = 5940 shorts, overlays image after conv1
    unsigned short* x4l = ub + 5952;   // [35][72]  = 2520 shorts
    unsigned short* x6l = ub + 8480;   // [15][64]  =  960 shorts (byte 16960, 16B aligned)

    const int img = blockIdx.x;
    const int tid = threadIdx.x;
    const int wave = tid >> 6, lane = tid & 63;
    const int col = lane & 15, quad = lane >> 4;

    if (tid < 215) red[tid] = 0.f;

    // stage image: 2304 float4 coalesced, convert once to bf16
    {
        const float4* xs = (const float4*)(x + (size_t)img * 9216);
        #pragma unroll
        for (int i = 0; i < 9; ++i) {
            const int idx = tid + i * 256;
            float4 v = xs[idx];
            const int fo = idx * 4;
            const int r = fo >> 6, cf = fo & 63;
            short4_t s;
            s[0] = (short)f2bf(v.x); s[1] = (short)f2bf(v.y);
            s[2] = (short)f2bf(v.z); s[3] = (short)f2bf(v.w);
            *(short4_t*)(ub + r * RS + cf) = s;
        }
    }
    const float bias0 = b1[col], bias1 = b1[col + 16];
    __syncthreads();

    // ---- conv1 compute: 11 m-tiles over 4 waves, N=32, K=192 (6 chunks); accs held in regs ----
    f32x4 c1a[3][2] = {};
    const unsigned short* w1b0 = w1p + (size_t)col * 192 + quad * 8;
    const unsigned short* w1b1 = w1b0 + 16 * 192;
    #pragma unroll
    for (int ti = 0; ti < 3; ++ti) {
        const int t = wave + ti * 4;
        if (t >= 11) break;
        const int posA = t * 16 + col;
        const int pm = posA < 165 ? posA : 164;
        const int oh = pm / 15, ow = pm % 15;
        #pragma unroll
        for (int c = 0; c < 6; ++c) {
            const int ic = c >> 1;
            const int kh = (c & 1) * 4 + quad;
            const unsigned short* ap = ub + (ic * 48 + oh * 4 + kh) * RS + ow * 4;
            short8 af;
            *(short4_t*)&af       = *(const short4_t*)ap;
            *((short4_t*)&af + 1) = *(const short4_t*)(ap + 4);
            short8 B0 = *(const short8*)(w1b0 + c * 32);
            short8 B1 = *(const short8*)(w1b1 + c * 32);
            c1a[ti][0] = MFMA_BF16(af, B0, c1a[ti][0], 0, 0, 0);
            c1a[ti][1] = MFMA_BF16(af, B1, c1a[ti][1], 0, 0, 0);
        }
    }
    __syncthreads();   // ALL image reads done -> safe to overlay x2l

    // ---- conv1 epilogue: bias/relu -> x2l (overlaid); ave1 partials ----
    #pragma unroll
    for (int ti = 0; ti < 3; ++ti) {
        const int t = wave + ti * 4;
        if (t >= 11) break;
        #pragma unroll
        for (int r = 0; r < 4; ++r) {
            const int pr = t * 16 + quad * 4 + r;
            float v0 = c1a[ti][0][r] + bias0;
            float v1 = c1a[ti][1][r] + bias1;
            float s = v0 + v1;
            s += __shfl_xor(s, 1); s += __shfl_xor(s, 2);
            s += __shfl_xor(s, 4); s += __shfl_xor(s, 8);
            if (pr < 165) {
                if (col == 0) atomicAdd(&red[pr], s);
                x2l[pr * 36 + col]      = f2bf(frelu(v0));
                x2l[pr * 36 + col + 16] = f2bf(frelu(v1));
            }
        }
    }
    __syncthreads();

    // ---- conv2: M=35 (3 m-tiles), wave owns 16-oc n-slice, K=288 (9 chunks) ----
    {
        const int oc2 = wave * 16 + col;
        const unsigned short* w2b = w2p + (size_t)oc2 * 288 + quad * 8;
        int aoff[3];
        #pragma unroll
        for (int mt = 0; mt < 3; ++mt) {
            int p = mt * 16 + col; p = p < 35 ? p : 34;
            aoff[mt] = ((p / 7) * 30 + (p % 7) * 2) * 36 + quad * 8;
        }
        f32x4 a2[3] = {};
        #pragma unroll
        for (int c = 0; c < 9; ++c) {
            short8 Bc = *(const short8*)(w2b + c * 32);
            const int koff = ((c / 3) * 15 + (c % 3)) * 36;
            #pragma unroll
            for (int mt = 0; mt < 3; ++mt) {
                const unsigned short* ap = x2l + aoff[mt] + koff;
                short8 af;
                *(short4_t*)&af       = *(const short4_t*)ap;
                *((short4_t*)&af + 1) = *(const short4_t*)(ap + 4);
                a2[mt] = MFMA_BF16(af, Bc, a2[mt], 0, 0, 0);
            }
        }
        const float bv2 = b2[oc2];
        #pragma unroll
        for (int mt = 0; mt < 3; ++mt) {
            #pragma unroll
            for (int r = 0; r < 4; ++r) {
                const int pr = mt * 16 + quad * 4 + r;
                float v = a2[mt][r] + bv2;
                float s = v;
                s += __shfl_xor(s, 1); s += __shfl_xor(s, 2);
                s += __shfl_xor(s, 4); s += __shfl_xor(s, 8);
                if (pr < 35) {
                    x4l[pr * 72 + oc2] = f2bf(frelu(v));   // disjoint from x2l reads
                    if (col == 0) atomicAdd(&red[165 + pr], s);
                }
            }
        }
    }
    __syncthreads();

    // ---- conv3: M=15 (1 m-tile), wave owns 16-oc n-slice, K=576 (18 chunks, dual chains) ----
    {
        const int oc3 = wave * 16 + col;
        const unsigned short* w3b = w3p + (size_t)oc3 * 576 + quad * 8;
        int p = col < 15 ? col : 14;
        const int abase = ((p / 5) * 7 + (p % 5)) * 72;
        f32x4 aA = {}, aB = {};
        #pragma unroll
        for (int cc = 0; cc < 9; ++cc) {
            const int kh = cc / 3, kw = cc % 3;
            const unsigned short* bp = x4l + abase + (kh * 7 + kw) * 72 + quad * 8;
            short8 af0 = *(const short8*)bp;          // ic 0..31   (16B aligned)
            short8 af1 = *(const short8*)(bp + 32);   // ic 32..63
            short8 B0 = *(const short8*)(w3b + (2 * cc) * 32);
            short8 B1 = *(const short8*)(w3b + (2 * cc + 1) * 32);
            aA = MFMA_BF16(af0, B0, aA, 0, 0, 0);
            aB = MFMA_BF16(af1, B1, aB, 0, 0, 0);
        }
        f32x4 a3 = aA + aB;
        const float bv3 = b3[oc3];
        #pragma unroll
        for (int r = 0; r < 4; ++r) {
            const int pr = quad * 4 + r;
            float v = a3[r] + bv3;
            float s = v;
            s += __shfl_xor(s, 1); s += __shfl_xor(s, 2);
            s += __shfl_xor(s, 4); s += __shfl_xor(s, 8);
            if (pr < 15) {
                x6l[pr * 64 + oc3] = f2bf(frelu(v));
                if (col == 0) atomicAdd(&red[200 + pr], s);
            }
        }
    }
    __syncthreads();

    // exports: coalesced x6 store + coalesced ave partials (img-major)
    if (tid < 120) ((float4*)(x6 + (size_t)img * 960))[tid] = ((const float4*)x6l)[tid];
    if (tid < 215) redbuf[(size_t)img * 216 + tid] = red[tid];
}

// ---------------- reduce: out[8192+row] = sum_img redbuf[img][row] * scale ----------------
__global__ __launch_bounds__(256) void reduce_aves(const float* __restrict__ redbuf, float* __restrict__ out) {
    const int row = blockIdx.x;
    float s = 0.f;
    for (int i = threadIdx.x; i < 4096; i += 256) s += redbuf[(size_t)i * 216 + row];
    s += __shfl_down(s, 32); s += __shfl_down(s, 16); s += __shfl_down(s, 8);
    s += __shfl_down(s, 4);  s += __shfl_down(s, 2);  s += __shfl_down(s, 1);
    __shared__ float wsum[4];
    if ((threadIdx.x & 63) == 0) wsum[threadIdx.x >> 6] = s;
    __syncthreads();
    if (threadIdx.x == 0)
        out[8192 + row] = (wsum[0] + wsum[1] + wsum[2] + wsum[3]) * (row < 165 ? 0.03125f : 0.015625f);
}

// ---------------- fc4+fc5: out[b,2] += relu(x6@w4p^T + b4) @ w5^T ----------------
// grid (128,8): 32 m-rows x 64 oc per block; wave owns 16-oc n-slice x 2 m-tiles, K=30 chunks.
__global__ __launch_bounds__(256) void fc45_mfma(const unsigned short* __restrict__ x6,
                                                 const unsigned short* __restrict__ w4p, const float* __restrict__ b4,
                                                 const float* __restrict__ w5, float* __restrict__ out) {
    __shared__ float outl[32][2];
    const int tid = threadIdx.x;
    const int wave = tid >> 6, lane = tid & 63;
    const int col = lane & 15, quad = lane >> 4;
    if (tid < 64) outl[tid >> 1][tid & 1] = 0.f;
    const int m0 = blockIdx.x * 32;
    const int oc = blockIdx.y * 64 + wave * 16 + col;

    const unsigned short* brow  = w4p + (size_t)oc * 960 + quad * 8;
    const unsigned short* arow0 = x6 + (size_t)(m0 + col) * 960 + quad * 8;
    const unsigned short* arow1 = arow0 + 16 * 960;
    f32x4 acc0 = {}, acc1 = {};
    __syncthreads();
    #pragma unroll 6
    for (int c = 0; c < 30; ++c) {
        short8 Bf = *(const short8*)(brow + c * 32);
        short8 a0 = *(const short8*)(arow0 + c * 32);
        short8 a1 = *(const short8*)(arow1 + c * 32);
        acc0 = MFMA_BF16(a0, Bf, acc0, 0, 0, 0);
        acc1 = MFMA_BF16(a1, Bf, acc1, 0, 0, 0);
    }
    const float bb = b4[oc], u0 = w5[oc], u1 = w5[512 + oc];
    #pragma unroll
    for (int mi = 0; mi < 2; ++mi) {
        const f32x4 acc = mi ? acc1 : acc0;
        #pragma unroll
        for (int r = 0; r < 4; ++r) {
            float h = frelu(acc[r] + bb);
            float l0 = h * u0, l1 = h * u1;
            l0 += __shfl_xor(l0, 1); l0 += __shfl_xor(l0, 2); l0 += __shfl_xor(l0, 4); l0 += __shfl_xor(l0, 8);
            l1 += __shfl_xor(l1, 1); l1 += __shfl_xor(l1, 2); l1 += __shfl_xor(l1, 4); l1 += __shfl_xor(l1, 8);
            if (col == 0) {
                atomicAdd(&outl[mi * 16 + quad * 4 + r][0], l0);
                atomicAdd(&outl[mi * 16 + quad * 4 + r][1], l1);
            }
        }
    }
    __syncthreads();
    if (tid < 64) atomicAdd(&out[(m0 + (tid >> 1)) * 2 + (tid & 1)], outl[tid >> 1][tid & 1]);
}

extern "C" void kernel_launch(void* const* d_in, const int* in_sizes, int n_in,
                              void* d_out, int out_size, void* d_ws, size_t ws_size,
                              hipStream_t stream) {
    const float* x  = (const float*)d_in[0];
    const float* w1 = (const float*)d_in[1];
    const float* b1 = (const float*)d_in[2];
    const float* w2 = (const float*)d_in[3];
    const float* b2 = (const float*)d_in[4];
    const float* w3 = (const float*)d_in[5];
    const float* b3 = (const float*)d_in[6];
    const float* w4 = (const float*)d_in[7];
    const float* b4 = (const float*)d_in[8];
    const float* w5 = (const float*)d_in[9];
    const float* b5 = (const float*)d_in[10];
    float* out = (float*)d_out;

    unsigned short* ws = (unsigned short*)d_ws;
    unsigned short* x6  = ws;                      // 3,932,160 ushort
    unsigned short* w1p = ws + 3932160;            //      6,144
    unsigned short* w2p = ws + 3938304;            //     18,432
    unsigned short* w3p = ws + 3956736;            //     36,864
    unsigned short* w4p = ws + 3993600;            //    491,520
    float* redbuf = (float*)((char*)d_ws + 8970240); // 4096*216 floats

    prep_kernel<<<2193, 256, 0, stream>>>(w1, w2, w3, w4, b5, w1p, w2p, w3p, w4p, out);
    fused_convs<<<BATCH, 256, 0, stream>>>(x, w1p, b1, w2p, b2, w3p, b3, x6, redbuf);
    reduce_aves<<<215, 256, 0, stream>>>(redbuf, out);
    fc45_mfma<<<dim3(128, 8), 256, 0, stream>>>(x6, w4p, b4, w5, out);
}